// Round 1
// baseline (6376.978 us; speedup 1.0000x reference)
//
#include <hip/hip_runtime.h>
#include <math.h>
#include <stdint.h>

#define B_    4096
#define SEQ_  19
#define E_    128
#define H_    1920
#define G4_   7680          // 4*H
#define KDIM  2176          // 2E + H
#define N2_   20

typedef __attribute__((ext_vector_type(8))) short bf16x8;
typedef __attribute__((ext_vector_type(4))) float f32x4;

__device__ __forceinline__ unsigned short f2bf(float f) {
  union { float f; unsigned int u; } v; v.f = f;
  unsigned int u = v.u;
  u += 0x7fffu + ((u >> 16) & 1u);   // RNE
  return (unsigned short)(u >> 16);
}
__device__ __forceinline__ float bf2f(unsigned short s) {
  union { unsigned int u; float f; } v; v.u = ((unsigned int)s) << 16;
  return v.f;
}
__device__ __forceinline__ float sigm(float x) { return 1.f / (1.f + __expf(-x)); }
__device__ __forceinline__ float tanh_fast(float x) {
  float ax = fabsf(x);
  float t = __expf(-2.f * ax);
  float r = (1.f - t) / (1.f + t);
  return copysignf(r, x);
}

// ---- weight permute + f32->bf16: W_perm[4u+g][k] = (k<256 ? W_ih : W_hh)[g*H+u][...]
__global__ __launch_bounds__(256) void wperm_kernel(const float* __restrict__ Wih,
                                                    const float* __restrict__ Whh,
                                                    unsigned short* __restrict__ Wp) {
  int k = blockIdx.x * 256 + threadIdx.x;
  int r = blockIdx.y;
  if (k >= KDIM) return;
  int u = r >> 2, g = r & 3;
  int orow = g * H_ + u;
  float v = (k < 256) ? Wih[(size_t)orow * 256 + k] : Whh[(size_t)orow * H_ + (k - 256)];
  Wp[(size_t)r * KDIM + k] = f2bf(v);
}

__global__ __launch_bounds__(256) void bias_kernel(const float* __restrict__ bi,
                                                   const float* __restrict__ bh,
                                                   float* __restrict__ bp) {
  int r = blockIdx.x * 256 + threadIdx.x;
  if (r >= G4_) return;
  int u = r >> 2, g = r & 3;
  int orow = g * H_ + u;
  bp[r] = bi[orow] + bh[orow];
}

// zero the h-region of A buffer (h0 = 0)
__global__ __launch_bounds__(256) void zeroh_kernel(unsigned short* __restrict__ Ab) {
  int u = blockIdx.x * 256 + threadIdx.x;
  if (u >= H_) return;
  Ab[(size_t)blockIdx.y * KDIM + 256 + u] = 0;
}

// write x_t = [emb(input1[b,t]) | pos[t]] (bf16) into A[:, 0:256]
__global__ __launch_bounds__(256) void copyx_kernel(const int* __restrict__ in1,
                                                    const float* __restrict__ emb,
                                                    const float* __restrict__ pos,
                                                    unsigned short* __restrict__ Adst, int t) {
  int b = blockIdx.x, e = threadIdx.x;
  float v;
  if (e < 128) v = emb[(size_t)in1[b * SEQ_ + t] * E_ + e];
  else         v = pos[t * E_ + (e - 128)];
  Adst[(size_t)b * KDIM + e] = f2bf(v);
}

// ---- fused gates GEMM + LSTM cell epilogue ----
// C(4096,7680) = A(4096,2176)bf16 @ W_perm(7680,2176)^T + bias; then per unit:
// i,f,g,o -> c' = f*c + i*g ; h = o*tanh(c') ; h(bf16) -> Anext[:,256+u]
__global__ __launch_bounds__(256) void gemm_lstm_kernel(
    const unsigned short* __restrict__ A,
    const unsigned short* __restrict__ W,
    const float* __restrict__ bias,
    float* __restrict__ Cst,
    unsigned short* __restrict__ Anext,
    int t0) {
  __shared__ __align__(16) unsigned short As[128 * 64];
  __shared__ __align__(16) unsigned short Bs[128 * 64];
  const int tid  = threadIdx.x;
  const int lane = tid & 63, wid = tid >> 6;
  const int wm = wid >> 1, wn = wid & 1;       // 2x2 waves of 64x64
  const int lr = lane & 15, lk = lane >> 4;
  const int m0 = blockIdx.y * 128, n0 = blockIdx.x * 128;

  f32x4 acc[4][4];
#pragma unroll
  for (int i = 0; i < 4; ++i)
#pragma unroll
    for (int j = 0; j < 4; ++j) acc[i][j] = (f32x4){0.f, 0.f, 0.f, 0.f};

  for (int kt = 0; kt < KDIM / 64; ++kt) {
    __syncthreads();
#pragma unroll
    for (int r = 0; r < 4; ++r) {
      int fi = r * 256 + tid;
      int row = fi >> 3, c8 = fi & 7;
      const unsigned short* ga = &A[(size_t)(m0 + row) * KDIM + kt * 64 + c8 * 8];
      const unsigned short* gb = &W[(size_t)(n0 + row) * KDIM + kt * 64 + c8 * 8];
      __builtin_amdgcn_global_load_lds((const __attribute__((address_space(1))) void*)ga,
                                       (__attribute__((address_space(3))) void*)&As[fi * 8],
                                       16, 0, 0);
      __builtin_amdgcn_global_load_lds((const __attribute__((address_space(1))) void*)gb,
                                       (__attribute__((address_space(3))) void*)&Bs[fi * 8],
                                       16, 0, 0);
    }
    __syncthreads();
#pragma unroll
    for (int ks = 0; ks < 2; ++ks) {
      bf16x8 af[4], bfr[4];
#pragma unroll
      for (int mi = 0; mi < 4; ++mi)
        af[mi] = *(const bf16x8*)&As[(wm * 64 + mi * 16 + lr) * 64 + ks * 32 + lk * 8];
#pragma unroll
      for (int ni = 0; ni < 4; ++ni)
        bfr[ni] = *(const bf16x8*)&Bs[(wn * 64 + ni * 16 + lr) * 64 + ks * 32 + lk * 8];
#pragma unroll
      for (int mi = 0; mi < 4; ++mi)
#pragma unroll
        for (int ni = 0; ni < 4; ++ni)
          acc[mi][ni] = __builtin_amdgcn_mfma_f32_16x16x32_bf16(af[mi], bfr[ni], acc[mi][ni], 0, 0, 0);
    }
  }

  // epilogue: interleaved gate columns (col = 4u+g); exchange within 4-lane groups
  const int mbase = m0 + wm * 64;
  const int bl = lane & ~3;
#pragma unroll
  for (int ni = 0; ni < 4; ++ni) {
    int colg = n0 + wn * 64 + ni * 16 + lr;
    float bn = bias[colg];
    int ug = colg >> 2;   // identical across the 4-lane group
#pragma unroll
    for (int mi = 0; mi < 4; ++mi) {
#pragma unroll
      for (int r = 0; r < 4; ++r) {
        float v = acc[mi][ni][r] + bn;
        float gi = __shfl(v, bl + 0);
        float gf = __shfl(v, bl + 1);
        float gg = __shfl(v, bl + 2);
        float go = __shfl(v, bl + 3);
        int mg = mbase + mi * 16 + lk * 4 + r;
        float cold = t0 ? 0.f : Cst[(size_t)mg * H_ + ug];
        float ii = sigm(gi), ff = sigm(gf);
        float gv = tanh_fast(gg), oo = sigm(go);
        float cn = ff * cold + ii * gv;
        float hh = oo * tanh_fast(cn);
        if ((lane & 3) == 0) {
          Cst[(size_t)mg * H_ + ug] = cn;
          Anext[(size_t)mg * KDIM + 256 + ug] = f2bf(hh);
        }
      }
    }
  }
}

// ---- final: per-row einsum + max + 2-class log-softmax ----
__global__ __launch_bounds__(64) void final_kernel(const unsigned short* __restrict__ Ah,
                                                   const int* __restrict__ in2,
                                                   const float* __restrict__ emb,
                                                   const float* __restrict__ linw,
                                                   const float* __restrict__ linb,
                                                   float* __restrict__ out) {
  __shared__ float hrow[H_];
  __shared__ float etab[N2_][E_];
  __shared__ float dlds[5][3][N2_];
  int b = blockIdx.x, l = threadIdx.x;

  for (int u = l; u < H_; u += 64) hrow[u] = bf2f(Ah[(size_t)b * KDIM + 256 + u]);
  for (int m = 0; m < N2_; ++m) {
    int idx = in2[b * N2_ + m];
    for (int e = l; e < E_; e += 64) etab[m][e] = emb[(size_t)idx * E_ + e];
  }
  __syncthreads();

  for (int cc = l; cc < 300; cc += 64) {
    int k = cc / 60, rem = cc % 60;
    int j = rem / 20, m = rem % 20;
    float s = 0.f;
    const float* hp = &hrow[k * 384 + j * 128];
#pragma unroll 4
    for (int e = 0; e < 128; ++e) s += hp[e] * etab[m][e];
    dlds[k][j][m] = s;
  }
  __syncthreads();

  float mx = -INFINITY;
  for (int cc = l; cc < 90; cc += 64) {
    int k = cc / 18, n = cc % 18;
    float rs = dlds[k][0][n] + dlds[k][1][n + 1] + dlds[k][2][n + 2];
    mx = fmaxf(mx, rs);
  }
#pragma unroll
  for (int off = 32; off; off >>= 1) mx = fmaxf(mx, __shfl_xor(mx, off));

  if (l == 0) {
    float z0 = mx * linw[0] + linb[0];
    float z1 = mx * linw[1] + linb[1];
    float zm = fmaxf(z0, z1);
    float lse = zm + logf(expf(z0 - zm) + expf(z1 - zm));
    out[b * 2 + 0] = z0 - lse;
    out[b * 2 + 1] = z1 - lse;
  }
}

extern "C" void kernel_launch(void* const* d_in, const int* in_sizes, int n_in,
                              void* d_out, int out_size, void* d_ws, size_t ws_size,
                              hipStream_t stream) {
  (void)in_sizes; (void)n_in; (void)out_size; (void)ws_size;
  const int*   in1  = (const int*)d_in[0];
  const int*   in2  = (const int*)d_in[1];
  const float* emb  = (const float*)d_in[2];
  const float* pos  = (const float*)d_in[3];
  const float* Wih  = (const float*)d_in[4];
  const float* Whh  = (const float*)d_in[5];
  const float* bih  = (const float*)d_in[6];
  const float* bhh  = (const float*)d_in[7];
  const float* linw = (const float*)d_in[8];
  const float* linb = (const float*)d_in[9];
  float* out = (float*)d_out;

  char* ws = (char*)d_ws;
  const size_t WPERM_B = (size_t)G4_ * KDIM * 2;   // 33,423,360
  const size_t ABUF_B  = (size_t)B_ * KDIM * 2;    // 17,825,792
  const size_t CST_B   = (size_t)B_ * H_ * 4;      // 31,457,280
  unsigned short* Wp  = (unsigned short*)(ws);
  unsigned short* A0  = (unsigned short*)(ws + WPERM_B);
  unsigned short* A1  = (unsigned short*)(ws + WPERM_B + ABUF_B);
  float*          Cst = (float*)(ws + WPERM_B + 2 * ABUF_B);
  float*          bp  = (float*)(ws + WPERM_B + 2 * ABUF_B + CST_B);

  // prep (must rerun every call: ws is re-poisoned)
  wperm_kernel<<<dim3(9, G4_), 256, 0, stream>>>(Wih, Whh, Wp);
  bias_kernel<<<dim3((G4_ + 255) / 256), 256, 0, stream>>>(bih, bhh, bp);
  zeroh_kernel<<<dim3(8, B_), 256, 0, stream>>>(A0);
  copyx_kernel<<<dim3(B_), 256, 0, stream>>>(in1, emb, pos, A0, 0);

  unsigned short* Abufs[2] = {A0, A1};
  for (int t = 0; t < SEQ_; ++t) {
    unsigned short* Acur = Abufs[t & 1];
    unsigned short* Anxt = Abufs[(t + 1) & 1];
    gemm_lstm_kernel<<<dim3(G4_ / 128, B_ / 128), 256, 0, stream>>>(
        Acur, Wp, bp, Cst, Anxt, t == 0 ? 1 : 0);
    if (t + 1 < SEQ_)
      copyx_kernel<<<dim3(B_), 256, 0, stream>>>(in1, emb, pos, Anxt, t + 1);
  }
  final_kernel<<<dim3(B_), 64, 0, stream>>>(Abufs[SEQ_ & 1], in2, emb, linw, linb, out);
}